// Round 5
// baseline (34.120 us; speedup 1.0000x reference)
//
#include <hip/hip_runtime.h>

#define B_ 4
#define C_ 64
#define H_ 128
#define W_ 128
#define R_ 8
#define LOG2E 1.44269504088896340736f

typedef float        v2f __attribute__((ext_vector_type(2)));
typedef unsigned int v2u __attribute__((ext_vector_type(2)));

// packed 2^x via magic-round + deg-3 poly + integer exponent insert.
// valid for |x| < ~120 (ours <= ~75); rel err <= 8e-4.
__device__ __forceinline__ v2f exp2p2(v2f x) {
    v2f t  = x + 12582912.0f;            // 1.5*2^23: rndne(x) lands in low mantissa (RTNE)
    v2f nf = t - 12582912.0f;
    v2f f  = x - nf;                     // f in [-0.5, 0.5]
    v2f p  = __builtin_elementwise_fma((v2f){0.0555041086f, 0.0555041086f}, f,
                                       (v2f){0.2402265070f, 0.2402265070f});
    p = __builtin_elementwise_fma(p, f, (v2f){0.6931471806f, 0.6931471806f});
    p = __builtin_elementwise_fma(p, f, (v2f){1.0f, 1.0f});
    v2u e = __builtin_bit_cast(v2u, t) << 23;          // n << 23 (low 9 bits of t)
    return __builtin_bit_cast(v2f, __builtin_bit_cast(v2u, p) + e);
}
__device__ __forceinline__ float exp2p1(float x) {
    float t  = x + 12582912.0f;
    float nf = t - 12582912.0f;
    float f  = x - nf;
    float p  = __builtin_fmaf(0.0555041086f, f, 0.2402265070f);
    p = __builtin_fmaf(p, f, 0.6931471806f);
    p = __builtin_fmaf(p, f, 1.0f);
    unsigned e = __builtin_bit_cast(unsigned, t) << 23;
    return __builtin_bit_cast(float, __builtin_bit_cast(unsigned, p) + e);
}

// HALF=0: prel indexed by window row i (rel_h); HALF=1: by window col j (rel_w).
template<int HALF>
__device__ __forceinline__ void sa_body(int x, int y0,
    const float* __restrict__ f1p, const float* __restrict__ f2p,
    const float* __restrict__ relp, float* __restrict__ outp)
{
    v2f   rl01 = {relp[0], relp[1]};
    v2f   rl23 = {relp[2], relp[3]};
    float rl4  = relp[4];

    int coff[5]; float msk[5];
    #pragma unroll
    for (int j = 0; j < 5; ++j) {
        const int kx = x + j - 2;
        coff[j] = kx < 0 ? 0 : (kx > W_ - 1 ? W_ - 1 : kx);
        msk[j]  = (kx >= 0 && kx < W_) ? 1.0f : 0.0f;
    }

    // packed rolling window: image row (y0 + d) lives in slot (d + 2) % 5
    v2f wa[5], wb[5]; float wc[5];

    #pragma unroll
    for (int t = 0; t < 4; ++t) {
        const int ky = y0 + t - 2;
        if (ky >= 0) {                        // scalar branch (y0 wave-uniform)
            const float* rp = f2p + ky * W_;
            wa[t] = (v2f){ rp[coff[0]] * msk[0], rp[coff[1]] * msk[1] };
            wb[t] = (v2f){ rp[coff[2]],          rp[coff[3]] * msk[3] };   // col 2 == x, always valid
            wc[t] = rp[coff[4]] * msk[4];
        } else {
            wa[t] = (v2f){0.f, 0.f}; wb[t] = (v2f){0.f, 0.f}; wc[t] = 0.f;
        }
    }

    #pragma unroll
    for (int r = 0; r < R_; ++r) {
        {   // load image row y0+r+2 into slot (r+4)%5
            const int ky = y0 + r + 2;
            const int slot = (r + 4) % 5;
            if (ky < H_) {
                const float* rp = f2p + ky * W_;
                wa[slot] = (v2f){ rp[coff[0]] * msk[0], rp[coff[1]] * msk[1] };
                wb[slot] = (v2f){ rp[coff[2]],          rp[coff[3]] * msk[3] };
                wc[slot] = rp[coff[4]] * msk[4];
            } else {
                wa[slot] = (v2f){0.f, 0.f}; wb[slot] = (v2f){0.f, 0.f}; wc[slot] = 0.f;
            }
        }

        const int y = y0 + r;
        const float q2 = f1p[y * W_ + x] * LOG2E;
        const v2f q2v = {q2, q2};
        const v2f prA = q2v * rl01;          // {q2*rel0, q2*rel1}
        const v2f prB = q2v * rl23;          // {q2*rel2, q2*rel3}
        const float prC = q2 * rl4;

        v2f sA = {0.f, 0.f}, dA = {0.f, 0.f};
        v2f sB = {0.f, 0.f}, dB = {0.f, 0.f};
        float ss = 0.f, ds = 0.f;

        #pragma unroll
        for (int i = 0; i < 5; ++i) {
            const int sl = (r + i) % 5;
            const float pri = (i == 0) ? prA.x : (i == 1) ? prA.y
                            : (i == 2) ? prB.x : (i == 3) ? prB.y : prC;
            const v2f pra = (HALF == 0) ? (v2f){pri, pri} : prA;
            const v2f prb = (HALF == 0) ? (v2f){pri, pri} : prB;
            {   const v2f v = wa[sl];
                const v2f sc = __builtin_elementwise_fma(v, q2v, pra);
                const v2f p  = exp2p2(sc);
                sA += p; dA = __builtin_elementwise_fma(p, v, dA); }
            {   const v2f v = wb[sl];
                const v2f sc = __builtin_elementwise_fma(v, q2v, prb);
                const v2f p  = exp2p2(sc);
                sB += p; dB = __builtin_elementwise_fma(p, v, dB); }
        }
        // col-4 taps, paired across rows (0,1) and (2,3)
        {   const v2f v  = { wc[(r + 0) % 5], wc[(r + 1) % 5] };
            const v2f pr = (HALF == 0) ? prA : (v2f){prC, prC};
            const v2f sc = __builtin_elementwise_fma(v, q2v, pr);
            const v2f p  = exp2p2(sc);
            sA += p; dA = __builtin_elementwise_fma(p, v, dA); }
        {   const v2f v  = { wc[(r + 2) % 5], wc[(r + 3) % 5] };
            const v2f pr = (HALF == 0) ? prB : (v2f){prC, prC};
            const v2f sc = __builtin_elementwise_fma(v, q2v, pr);
            const v2f p  = exp2p2(sc);
            sB += p; dB = __builtin_elementwise_fma(p, v, dB); }
        // scalar tail: row 4, col 4 (prel = prC for both halves)
        {   const float v  = wc[(r + 4) % 5];
            const float sc = __builtin_fmaf(q2, v, prC);
            const float p  = exp2p1(sc);
            ss += p; ds = __builtin_fmaf(p, v, ds); }

        const v2f st = sA + sB, dt = dA + dB;
        const float sum = st.x + st.y + ss;
        const float dot = dt.x + dt.y + ds;
        outp[y * W_ + x] = __fdividef(dot, sum);
    }
}

__global__ __launch_bounds__(256) void sa_kernel(
    const float* __restrict__ f1, const float* __restrict__ f2,
    const float* __restrict__ relh, const float* __restrict__ relw,
    float* __restrict__ out)
{
    const int tid   = threadIdx.x;
    const int x     = tid & (W_ - 1);
    const int s     = tid >> 7;
    const int blk   = blockIdx.x;
    const int spair = blk & 7;
    const int bc    = blk >> 3;
    const int c     = bc & (C_ - 1);
    const int b     = bc >> 6;
    const int y0    = __builtin_amdgcn_readfirstlane((spair * 2 + s) * R_);

    const size_t img = (size_t)(b * C_ + c) * (H_ * W_);
    const float* f1p = f1 + img;
    const float* f2p = f2 + img;

    const int c_out = (c & 7) * 8 + (c >> 3);   // einsum channel transpose
    float* outp = out + (size_t)(b * C_ + c_out) * (H_ * W_);

    if (c < C_ / 2) sa_body<0>(x, y0, f1p, f2p, relh + c * 5, outp);
    else            sa_body<1>(x, y0, f1p, f2p, relw + (c - C_ / 2) * 5, outp);
}

extern "C" void kernel_launch(void* const* d_in, const int* in_sizes, int n_in,
                              void* d_out, int out_size, void* d_ws, size_t ws_size,
                              hipStream_t stream) {
    const float* f1   = (const float*)d_in[0];
    const float* f2   = (const float*)d_in[1];
    const float* relh = (const float*)d_in[2];
    const float* relw = (const float*)d_in[3];
    float* out = (float*)d_out;

    const int grid = B_ * C_ * (H_ / R_ / 2);   // 2048 blocks
    sa_kernel<<<grid, 256, 0, stream>>>(f1, f2, relh, relw, out);
}

// Round 6
// 24.928 us; speedup vs baseline: 1.3687x; 1.3687x over previous
//
#include <hip/hip_runtime.h>

#define B_ 4
#define C_ 64
#define H_ 128
#define W_ 128
#define R_ 4
#define NROWS (R_ + 4)
#define LOG2E 1.44269504088896340736f

// HALF=0: rel indexed by window row i (rel_h); HALF=1: by window col j (rel_w).
// All global loads for the strip are issued upfront as one deep clause.
template<int HALF>
__device__ __forceinline__ void sa_body(int x, int y0,
    const float* __restrict__ f1p, const float* __restrict__ f2p,
    const float* __restrict__ relp, float* __restrict__ outp)
{
    float rel5[5];
    #pragma unroll
    for (int k = 0; k < 5; ++k) rel5[k] = relp[k];

    // clamped per-lane column offsets (loop-invariant) + border masks
    int coff[5]; float msk[5];
    #pragma unroll
    for (int j = 0; j < 5; ++j) {
        const int kx = x + j - 2;
        coff[j] = kx < 0 ? 0 : (kx > W_ - 1 ? W_ - 1 : kx);
        msk[j]  = (kx >= 0 && kx < W_) ? 1.0f : 0.0f;
    }

    // ---- deep load clause: 8 rows x 5 taps + 4 q values, no inter-load deps ----
    float w[NROWS][5];
    #pragma unroll
    for (int t = 0; t < NROWS; ++t) {
        const int ky = y0 + t - 2;               // wave-uniform -> scalar branch
        if (ky >= 0 && ky < H_) {
            const float* rp = f2p + ky * W_;
            #pragma unroll
            for (int j = 0; j < 5; ++j) w[t][j] = rp[coff[j]];
        } else {
            #pragma unroll
            for (int j = 0; j < 5; ++j) w[t][j] = 0.0f;
        }
    }
    float qv[R_];
    #pragma unroll
    for (int r = 0; r < R_; ++r) qv[r] = f1p[(y0 + r) * W_ + x];

    // border fixup (after the whole clause is issued)
    #pragma unroll
    for (int t = 0; t < NROWS; ++t) {
        #pragma unroll
        for (int j = 0; j < 5; ++j) w[t][j] *= msk[j];
    }

    // ---- compute: 4 outputs, 25 taps each, all window data in registers ----
    #pragma unroll
    for (int r = 0; r < R_; ++r) {
        const float q2 = qv[r] * LOG2E;          // fold log2(e) into q
        float prel[5];
        #pragma unroll
        for (int k = 0; k < 5; ++k) prel[k] = q2 * rel5[k];

        // no max-subtraction: |q2*(v+rel)| < ~80 << 128, exp2 can't overflow
        float sum0 = 0.f, sum1 = 0.f, dot0 = 0.f, dot1 = 0.f;
        #pragma unroll
        for (int i = 0; i < 5; ++i) {
            #pragma unroll
            for (int j = 0; j < 5; ++j) {
                const float v  = w[r + i][j];
                const float sc = __builtin_fmaf(q2, v, prel[HALF == 0 ? i : j]);
                const float p  = __builtin_amdgcn_exp2f(sc);
                if (((i * 5 + j) & 1) == 0) { sum0 += p; dot0 = __builtin_fmaf(p, v, dot0); }
                else                        { sum1 += p; dot1 = __builtin_fmaf(p, v, dot1); }
            }
        }
        const float sum = sum0 + sum1;
        const float dot = dot0 + dot1;
        outp[(y0 + r) * W_ + x] = dot * __builtin_amdgcn_rcpf(sum);
    }
}

__global__ __launch_bounds__(256) void sa_kernel(
    const float* __restrict__ f1, const float* __restrict__ f2,
    const float* __restrict__ relh, const float* __restrict__ relw,
    float* __restrict__ out)
{
    const int tid   = threadIdx.x;
    const int x     = tid & (W_ - 1);
    const int s     = tid >> 7;                 // strip within pair (wave-uniform)
    const int blk   = blockIdx.x;
    const int spair = blk & (H_ / R_ / 2 - 1);  // 16 strip-pairs per image
    const int bc    = blk >> 4;
    const int c     = bc & (C_ - 1);
    const int b     = bc >> 6;
    const int y0    = __builtin_amdgcn_readfirstlane((spair * 2 + s) * R_);

    const size_t img = (size_t)(b * C_ + c) * (H_ * W_);
    const float* f1p = f1 + img;
    const float* f2p = f2 + img;

    const int c_out = (c & 7) * 8 + (c >> 3);   // einsum channel transpose
    float* outp = out + (size_t)(b * C_ + c_out) * (H_ * W_);

    if (c < C_ / 2) sa_body<0>(x, y0, f1p, f2p, relh + c * 5, outp);
    else            sa_body<1>(x, y0, f1p, f2p, relw + (c - C_ / 2) * 5, outp);
}

extern "C" void kernel_launch(void* const* d_in, const int* in_sizes, int n_in,
                              void* d_out, int out_size, void* d_ws, size_t ws_size,
                              hipStream_t stream) {
    const float* f1   = (const float*)d_in[0];
    const float* f2   = (const float*)d_in[1];
    const float* relh = (const float*)d_in[2];
    const float* relw = (const float*)d_in[3];
    float* out = (float*)d_out;

    const int grid = B_ * C_ * (H_ / R_ / 2);   // 4096 blocks, 16/CU
    sa_kernel<<<grid, 256, 0, stream>>>(f1, f2, relh, relw, out);
}

// Round 7
// 21.651 us; speedup vs baseline: 1.5759x; 1.1513x over previous
//
#include <hip/hip_runtime.h>

#define B_ 4
#define C_ 64
#define H_ 128
#define W_ 128
#define LOG2E 1.44269504088896340736f

typedef float v2f __attribute__((ext_vector_type(2)));

__device__ __forceinline__ v2f exp2v(v2f x) {
    return (v2f){ __builtin_amdgcn_exp2f(x.x), __builtin_amdgcn_exp2f(x.y) };
}

// Thread: 4 consecutive x (one aligned quad) x 4 consecutive y. Rolling 5-row window,
// each row 8 floats (x0-2 .. x0+5) built from 3 aligned float4 loads + multiplicative masks.
// HALF=0: rel indexed by window row i; HALF=1: by window col j.
template<int HALF>
__device__ __forceinline__ void sa_body(int x0, int y0,
    const float* __restrict__ f1p, const float* __restrict__ f2p,
    const float* __restrict__ relp, float* __restrict__ outp)
{
    float rel5[5];
    #pragma unroll
    for (int k = 0; k < 5; ++k) rel5[k] = relp[k];

    // x-halo masks and clamped aligned element offsets (loop-invariant)
    const float mL = (x0 > 0) ? 1.0f : 0.0f;
    const float mR = (x0 < W_ - 4) ? 1.0f : 0.0f;
    const int eM = (x0 >= 4) ? x0 - 4 : 0;
    const int eC = x0;
    const int eP = (x0 <= W_ - 8) ? x0 + 4 : W_ - 4;

    float w[5][8];   // rolling window: image row (y0 + s - 2) in slot s (mod 5)

    // helper expanded inline below via lambda
    auto load_row = [&](int slot, int ky) {
        const int kycl = ky < 0 ? 0 : (ky > H_ - 1 ? H_ - 1 : ky);
        const float rv = ((unsigned)ky < (unsigned)H_) ? 1.0f : 0.0f;
        const float* rp = f2p + kycl * W_;
        const float4 qm = *(const float4*)(rp + eM);
        const float4 q0 = *(const float4*)(rp + eC);
        const float4 qp = *(const float4*)(rp + eP);
        const float mLr = mL * rv, mRr = mR * rv;
        w[slot][0] = qm.z * mLr; w[slot][1] = qm.w * mLr;
        w[slot][2] = q0.x * rv;  w[slot][3] = q0.y * rv;
        w[slot][4] = q0.z * rv;  w[slot][5] = q0.w * rv;
        w[slot][6] = qp.x * mRr; w[slot][7] = qp.y * mRr;
    };

    #pragma unroll
    for (int t = 0; t < 4; ++t) load_row(t, y0 + t - 2);

    #pragma unroll
    for (int r = 0; r < 4; ++r) {
        load_row((r + 4) % 5, y0 + r + 2);

        const float4 q4 = *(const float4*)(f1p + (y0 + r) * W_ + x0);
        const float qs[4] = {q4.x, q4.y, q4.z, q4.w};
        float res[4];

        #pragma unroll
        for (int xo = 0; xo < 4; ++xo) {
            const float q2 = qs[xo] * LOG2E;
            const v2f q2v = {q2, q2};

            float pr[5];
            #pragma unroll
            for (int k = 0; k < 5; ++k) pr[k] = q2 * rel5[k];
            const v2f prA = {pr[0], pr[1]};
            const v2f prB = {pr[2], pr[3]};
            const float prC = pr[4];

            v2f s0 = {0.f, 0.f}, s1 = {0.f, 0.f};
            v2f d0 = {0.f, 0.f}, d1 = {0.f, 0.f};
            float lv[5];

            #pragma unroll
            for (int i = 0; i < 5; ++i) {
                const float* W8 = w[(r + i) % 5];
                const v2f va = {W8[xo + 0], W8[xo + 1]};
                const v2f vb = {W8[xo + 2], W8[xo + 3]};
                const v2f pa = (HALF == 0) ? (v2f){pr[i], pr[i]} : prA;
                const v2f pb = (HALF == 0) ? (v2f){pr[i], pr[i]} : prB;
                const v2f p0 = exp2v(__builtin_elementwise_fma(va, q2v, pa));
                s0 += p0; d0 = __builtin_elementwise_fma(p0, va, d0);
                const v2f p1 = exp2v(__builtin_elementwise_fma(vb, q2v, pb));
                s1 += p1; d1 = __builtin_elementwise_fma(p1, vb, d1);
                lv[i] = W8[xo + 4];
            }
            // leftover column j=4, paired across rows (0,1) and (2,3), scalar row 4
            {
                const v2f v = {lv[0], lv[1]};
                const v2f pp = (HALF == 0) ? (v2f){pr[0], pr[1]} : (v2f){prC, prC};
                const v2f p = exp2v(__builtin_elementwise_fma(v, q2v, pp));
                s0 += p; d0 = __builtin_elementwise_fma(p, v, d0);
            }
            {
                const v2f v = {lv[2], lv[3]};
                const v2f pp = (HALF == 0) ? (v2f){pr[2], pr[3]} : (v2f){prC, prC};
                const v2f p = exp2v(__builtin_elementwise_fma(v, q2v, pp));
                s1 += p; d1 = __builtin_elementwise_fma(p, v, d1);
            }
            float ss, ds;
            {
                const float pp = (HALF == 0) ? pr[4] : prC;
                const float p = __builtin_amdgcn_exp2f(__builtin_fmaf(q2, lv[4], pp));
                ss = p; ds = p * lv[4];
            }
            const v2f st = s0 + s1, dt = d0 + d1;
            const float sum = st.x + st.y + ss;
            const float dot = dt.x + dt.y + ds;
            res[xo] = dot * __builtin_amdgcn_rcpf(sum);
        }

        *(float4*)(outp + (y0 + r) * W_ + x0) = (float4){res[0], res[1], res[2], res[3]};
    }
}

__global__ __launch_bounds__(256) void sa_kernel(
    const float* __restrict__ f1, const float* __restrict__ f2,
    const float* __restrict__ relh, const float* __restrict__ relw,
    float* __restrict__ out)
{
    const int tid   = threadIdx.x;
    const int xq    = tid & 31;          // 32 x-quads span the full width
    const int ys    = tid >> 5;          // 8 y-strips of 4 rows
    const int blk   = blockIdx.x;
    const int chunk = blk & 3;           // 4 chunks of 32 rows per image
    const int bc    = blk >> 2;
    const int c     = bc & (C_ - 1);
    const int b     = bc >> 6;
    const int x0    = xq << 2;
    const int y0    = chunk * 32 + ys * 4;

    const size_t img = (size_t)(b * C_ + c) * (H_ * W_);
    const float* f1p = f1 + img;
    const float* f2p = f2 + img;

    const int c_out = (c & 7) * 8 + (c >> 3);   // einsum channel transpose
    float* outp = out + (size_t)(b * C_ + c_out) * (H_ * W_);

    if (c < C_ / 2) sa_body<0>(x0, y0, f1p, f2p, relh + c * 5, outp);
    else            sa_body<1>(x0, y0, f1p, f2p, relw + (c - C_ / 2) * 5, outp);
}

extern "C" void kernel_launch(void* const* d_in, const int* in_sizes, int n_in,
                              void* d_out, int out_size, void* d_ws, size_t ws_size,
                              hipStream_t stream) {
    const float* f1   = (const float*)d_in[0];
    const float* f2   = (const float*)d_in[1];
    const float* relh = (const float*)d_in[2];
    const float* relw = (const float*)d_in[3];
    float* out = (float*)d_out;

    const int grid = B_ * C_ * 4;   // 1024 blocks, 4/CU
    sa_kernel<<<grid, 256, 0, stream>>>(f1, f2, relh, relw, out);
}